// Round 5
// baseline (31.223 us; speedup 1.0000x reference)
//
#include <hip/hip_runtime.h>
#include <hip/hip_bf16.h>

// GATv2 dense complete-graph, B=32, W=128 (in-feat), F=64 (nodes), H=2, D=128.
// K1: LDS-free projection, 4n x 4c x (l,r) register tile, shfl-reduced over w.
// K2: scores with 8i x 4j register tile (d on lanes, butterfly-reduced),
//     no-max softmax, register-tiled aggregate with in-thread head mean.

constexpr int kB = 32, kW = 128, kF = 64, kH = 2, kD = 128, kHD = 256;
constexpr float kNeg = 0.2f;

__device__ __forceinline__ float lrelu(float v) { return fmaxf(v, kNeg * v); }

// ---------------- K1: projection ----------------
// grid = B*8 (c-slices of 32), block = 512 (wave = c-quad).
// lane = ws(2b)<<4 | nq(4b). thread: 4n x 4c x (l,r) over 32 w's.
__global__ __launch_bounds__(512, 2) void gat_proj(
    const float* __restrict__ x, const float* __restrict__ Wl,
    const float* __restrict__ Wr, float* __restrict__ elw,
    float* __restrict__ erw) {
  const int t = threadIdx.x;
  const int b = blockIdx.x >> 3;
  const int c0 = ((blockIdx.x & 7) << 5) + ((t >> 6) << 2);
  const int lane = t & 63;
  const int ws = lane >> 4;        // w-quarter on lane bits 4..5
  const int n0 = (lane & 15) << 2; // n-quad

  const float* xp = x + b * (kW * kF) + (ws * 32) * kF + n0;
  const float* wlp = Wl + (ws * 32) * kHD + c0;
  const float* wrp = Wr + (ws * 32) * kHD + c0;

  float al[4][4] = {};
  float ar[4][4] = {};
#pragma unroll 8
  for (int k = 0; k < 32; ++k) {
    const float4 xv = *(const float4*)xp;
    const float4 wl = *(const float4*)wlp;
    const float4 wr = *(const float4*)wrp;
    const float xa[4] = {xv.x, xv.y, xv.z, xv.w};
    const float wa[4] = {wl.x, wl.y, wl.z, wl.w};
    const float ra[4] = {wr.x, wr.y, wr.z, wr.w};
#pragma unroll
    for (int i = 0; i < 4; ++i)
#pragma unroll
      for (int j = 0; j < 4; ++j) {
        al[i][j] = fmaf(xa[i], wa[j], al[i][j]);
        ar[i][j] = fmaf(xa[i], ra[j], ar[i][j]);
      }
    xp += kF;
    wlp += kHD;
    wrp += kHD;
  }

  // butterfly-reduce over ws (lane bits 4..5)
#pragma unroll
  for (int off = 16; off <= 32; off <<= 1)
#pragma unroll
    for (int i = 0; i < 4; ++i)
#pragma unroll
      for (int j = 0; j < 4; ++j) {
        al[i][j] += __shfl_xor(al[i][j], off);
        ar[i][j] += __shfl_xor(ar[i][j], off);
      }

  // lane-masked stores: ws == i stores n-row i (all lanes hold full sums)
  const int base = (b * kF + n0) * kHD + c0;
#pragma unroll
  for (int i = 0; i < 4; ++i) {
    if (ws == i) {
      *(float4*)&elw[base + i * kHD] =
          make_float4(al[i][0], al[i][1], al[i][2], al[i][3]);
      *(float4*)&erw[base + i * kHD] =
          make_float4(ar[i][0], ar[i][1], ar[i][2], ar[i][3]);
    }
  }
}

// ---------------- K2: attention (both heads per block) ----------------
// grid = B*8 (i-tiles of 8), block = 512.
__global__ __launch_bounds__(512, 2) void gat_attn(
    const float* __restrict__ elw, const float* __restrict__ erw,
    const float* __restrict__ attn_a, const float* __restrict__ bias,
    float* __restrict__ out) {
  __shared__ float el[kH][kF][kD + 4];  // 67.6 KB
  __shared__ float er[kH][8][kD + 4];   //  8.4 KB
  __shared__ float av[kH][kD];          //  1 KB
  __shared__ float als[kH][kF][8];      // alphas [h][j][i], 4 KB
  __shared__ float sbuf[kH][8][4];      // per-wave softmax denoms, 256 B

  const int t = threadIdx.x;
  const int b = blockIdx.x >> 3;
  const int i0 = (blockIdx.x & 7) << 3;

  // ---- stage: el (both heads, 64 src rows), er (8 dst rows), attn_a ----
  {
    const float* elb = elw + b * (kF * kHD);
#pragma unroll
    for (int k = 0; k < 8; ++k) {
      const int s = t + (k << 9);  // 0..4095 float4 slots
      const int h = s >> 11;
      const int n = (s >> 5) & 63;
      const int dv = (s & 31) << 2;
      *(float4*)&el[h][n][dv] = *(const float4*)&elb[n * kHD + h * kD + dv];
    }
    const float* erb = erw + (b * kF + i0) * kHD;
    {
      const int h = t >> 8;
      const int r = (t >> 5) & 7;
      const int dv = (t & 31) << 2;
      *(float4*)&er[h][r][dv] = *(const float4*)&erb[r * kHD + h * kD + dv];
    }
    if (t < kH * kD) av[t >> 7][t & 127] = attn_a[t];
  }
  __syncthreads();

  // ---- scores: t = h(1b) | jhi(2b) | dq(4b) | jq(2b); acc 8i x 4j ----
  {
    const int h = t >> 8;
    const int jhi = (t >> 6) & 3;
    const int lane = t & 63;
    const int dq = lane >> 2;  // 16 d-groups of 8, on lane bits 2..5
    const int jq = lane & 3;
    const int j0 = jhi * 16 + jq * 4;
    const int d0 = dq * 8;

    float s[8][4] = {};
#pragma unroll
    for (int dd = 0; dd < 2; ++dd) {
      const int d = d0 + dd * 4;
      const float4 a4 = *(const float4*)&av[h][d];
      const float aa[4] = {a4.x, a4.y, a4.z, a4.w};
      float ea[4][4];
#pragma unroll
      for (int jj = 0; jj < 4; ++jj) {
        const float4 e4 = *(const float4*)&el[h][j0 + jj][d];
        ea[jj][0] = e4.x; ea[jj][1] = e4.y; ea[jj][2] = e4.z; ea[jj][3] = e4.w;
      }
#pragma unroll
      for (int ii = 0; ii < 8; ++ii) {
        const float4 r4 = *(const float4*)&er[h][ii][d];
        const float ra[4] = {r4.x, r4.y, r4.z, r4.w};
#pragma unroll
        for (int jj = 0; jj < 4; ++jj)
#pragma unroll
          for (int k = 0; k < 4; ++k)
            s[ii][jj] = fmaf(aa[k], lrelu(ea[jj][k] + ra[k]), s[ii][jj]);
      }
    }

    // butterfly over dq (lane bits 2..5): full scores in every lane
#pragma unroll
    for (int off = 4; off <= 32; off <<= 1)
#pragma unroll
      for (int ii = 0; ii < 8; ++ii)
#pragma unroll
        for (int jj = 0; jj < 4; ++jj)
          s[ii][jj] += __shfl_xor(s[ii][jj], off);

    // exp (no max-subtraction: |e| < ~6 for N(0,1) scores) + 16-j partials
    float p[8][4], ps[8];
#pragma unroll
    for (int ii = 0; ii < 8; ++ii) {
      p[ii][0] = __expf(s[ii][0]);
      p[ii][1] = __expf(s[ii][1]);
      p[ii][2] = __expf(s[ii][2]);
      p[ii][3] = __expf(s[ii][3]);
      ps[ii] = (p[ii][0] + p[ii][1]) + (p[ii][2] + p[ii][3]);
    }
#pragma unroll
    for (int off = 1; off <= 2; off <<= 1)
#pragma unroll
      for (int ii = 0; ii < 8; ++ii) ps[ii] += __shfl_xor(ps[ii], off);

    // one lane per (h,jhi,ii) writes the 16-j partial denom
#pragma unroll
    for (int ii = 0; ii < 8; ++ii)
      if (lane == (ii << 2)) sbuf[h][ii][jhi] = ps[ii];
    __syncthreads();

    // combine 4 jhi partials -> inv denom; write alphas i-contiguous
    float inv[8];
#pragma unroll
    for (int ii = 0; ii < 8; ++ii) {
      const float4 d4 = *(const float4*)&sbuf[h][ii][0];
      inv[ii] = __builtin_amdgcn_rcpf((d4.x + d4.y) + (d4.z + d4.w));
    }
#pragma unroll
    for (int jj = 0; jj < 4; ++jj) {
      if (dq == jj) {  // 4 lanes (one per jq) write row j0+jj
        const int j = j0 + jj;
        *(float4*)&als[h][j][0] =
            make_float4(p[0][jj] * inv[0], p[1][jj] * inv[1],
                        p[2][jj] * inv[2], p[3][jj] * inv[3]);
        *(float4*)&als[h][j][4] =
            make_float4(p[4][jj] * inv[4], p[5][jj] * inv[5],
                        p[6][jj] * inv[6], p[7][jj] * inv[7]);
      }
    }
  }
  __syncthreads();

  // ---- aggregate: t = iq(2b) | dqh(1b) | jp(2b) | dql(4b) ----
  // acc[2h][2i][4d]; head mean in-thread; butterfly over jp.
  {
    const int iq = t >> 7;          // i-pair index (0..3)
    const int dqh = (t >> 6) & 1;
    const int lane = t & 63;
    const int jp = lane >> 4;       // j-quarter on lane bits 4..5
    const int dql = lane & 15;
    const int d0 = ((dqh << 4) + dql) << 2;
    const int iq2 = iq << 1;

    float acc[2][2][4] = {};
#pragma unroll
    for (int jj = 0; jj < 16; ++jj) {
      const int j = (jp << 4) + jj;
      const float2 a0 = *(const float2*)&als[0][j][iq2];
      const float2 a1 = *(const float2*)&als[1][j][iq2];
      const float4 e0 = *(const float4*)&el[0][j][d0];
      const float4 e1 = *(const float4*)&el[1][j][d0];
      acc[0][0][0] = fmaf(a0.x, e0.x, acc[0][0][0]);
      acc[0][0][1] = fmaf(a0.x, e0.y, acc[0][0][1]);
      acc[0][0][2] = fmaf(a0.x, e0.z, acc[0][0][2]);
      acc[0][0][3] = fmaf(a0.x, e0.w, acc[0][0][3]);
      acc[0][1][0] = fmaf(a0.y, e0.x, acc[0][1][0]);
      acc[0][1][1] = fmaf(a0.y, e0.y, acc[0][1][1]);
      acc[0][1][2] = fmaf(a0.y, e0.z, acc[0][1][2]);
      acc[0][1][3] = fmaf(a0.y, e0.w, acc[0][1][3]);
      acc[1][0][0] = fmaf(a1.x, e1.x, acc[1][0][0]);
      acc[1][0][1] = fmaf(a1.x, e1.y, acc[1][0][1]);
      acc[1][0][2] = fmaf(a1.x, e1.z, acc[1][0][2]);
      acc[1][0][3] = fmaf(a1.x, e1.w, acc[1][0][3]);
      acc[1][1][0] = fmaf(a1.y, e1.x, acc[1][1][0]);
      acc[1][1][1] = fmaf(a1.y, e1.y, acc[1][1][1]);
      acc[1][1][2] = fmaf(a1.y, e1.z, acc[1][1][2]);
      acc[1][1][3] = fmaf(a1.y, e1.w, acc[1][1][3]);
    }

    // butterfly over jp (lane bits 4..5)
#pragma unroll
    for (int off = 16; off <= 32; off <<= 1)
#pragma unroll
      for (int h = 0; h < 2; ++h)
#pragma unroll
        for (int ii = 0; ii < 2; ++ii)
#pragma unroll
          for (int k = 0; k < 4; ++k)
            acc[h][ii][k] += __shfl_xor(acc[h][ii][k], off);

    // head mean + bias; lane jp==k stores d-row d0+k (float2 over i-pair)
    const float4 b0 = *(const float4*)&bias[d0];
    const float4 b1 = *(const float4*)&bias[kD + d0];
    const float bs[4] = {b0.x + b1.x, b0.y + b1.y, b0.z + b1.z, b0.w + b1.w};
    const int ig = i0 + iq2;
    float* ob = out + b * (kD * kF) + ig;
#pragma unroll
    for (int k = 0; k < 4; ++k) {
      if (jp == k) {
        float2 v;
        v.x = 0.5f * (acc[0][0][k] + acc[1][0][k] + bs[k]);
        v.y = 0.5f * (acc[0][1][k] + acc[1][1][k] + bs[k]);
        *(float2*)&ob[(d0 + k) * kF] = v;
      }
    }
  }
}

extern "C" void kernel_launch(void* const* d_in, const int* in_sizes, int n_in,
                              void* d_out, int out_size, void* d_ws,
                              size_t ws_size, hipStream_t stream) {
  (void)in_sizes; (void)n_in; (void)ws_size; (void)out_size;
  const float* x = (const float*)d_in[0];
  const float* Wl = (const float*)d_in[1];
  const float* Wr = (const float*)d_in[2];
  const float* attn_a = (const float*)d_in[3];
  const float* bias = (const float*)d_in[4];
  float* out = (float*)d_out;

  float* elw = (float*)d_ws;                  // [B][64][256]
  float* erw = elw + (size_t)kB * kF * kHD;   // [B][64][256]

  gat_proj<<<dim3(kB * 8), dim3(512), 0, stream>>>(x, Wl, Wr, elw, erw);
  gat_attn<<<dim3(kB * 8), dim3(512), 0, stream>>>(elw, erw, attn_a, bias, out);
}

// Round 6
// 24.848 us; speedup vs baseline: 1.2565x; 1.2565x over previous
//
#include <hip/hip_runtime.h>
#include <hip/hip_bf16.h>

// GATv2 dense complete-graph, B=32, W=128 (in-feat), F=64 (nodes), H=2, D=128.
// K1: el/er projection — x tile in LDS, W streamed from global (L2).
// K2: per (b, i-tile of 8): scores (el from LDS; er/av broadcast from L1) +
//     in-wave shfl softmax + register-blocked aggregate + head-mean.

constexpr int kB = 32, kW = 128, kF = 64, kH = 2, kD = 128, kHD = 256;
constexpr float kNeg = 0.2f;

__device__ __forceinline__ float lrelu(float v) { return fmaxf(v, kNeg * v); }

// ---------------- K1: projection ----------------
// grid = B*8 (8 column-slices of 32), block = 512.
__global__ __launch_bounds__(512) void gat_proj(
    const float* __restrict__ x, const float* __restrict__ Wl,
    const float* __restrict__ Wr, float* __restrict__ elw,
    float* __restrict__ erw) {
  __shared__ float xw[kW][kF + 4];
  const int b = blockIdx.x >> 3;
  const int c0 = (blockIdx.x & 7) << 5;
  const int t = threadIdx.x;

  const float* xb = x + b * (kW * kF);
#pragma unroll
  for (int k = 0; k < 16; ++k) {
    const int idx = t + (k << 9);
    xw[idx >> 6][idx & 63] = xb[idx];  // xw[w][n] = x[b][w][n]
  }
  __syncthreads();

  const int c = c0 + (t & 31);
  const int n0 = (t >> 5) << 2;  // 4 rows per thread
  float accl[4] = {0.f, 0.f, 0.f, 0.f};
  float accr[4] = {0.f, 0.f, 0.f, 0.f};
  const float* wlp = Wl + c;
  const float* wrp = Wr + c;

#pragma unroll 8
  for (int w = 0; w < kW; ++w) {
    const float wl = wlp[w * kHD];   // global, L2-hit, VMEM pipe
    const float wr = wrp[w * kHD];
    const float4 xa = *(const float4*)&xw[w][n0];
    accl[0] = fmaf(xa.x, wl, accl[0]); accr[0] = fmaf(xa.x, wr, accr[0]);
    accl[1] = fmaf(xa.y, wl, accl[1]); accr[1] = fmaf(xa.y, wr, accr[1]);
    accl[2] = fmaf(xa.z, wl, accl[2]); accr[2] = fmaf(xa.z, wr, accr[2]);
    accl[3] = fmaf(xa.w, wl, accl[3]); accr[3] = fmaf(xa.w, wr, accr[3]);
  }

  const int base = (b * kF + n0) * kHD + c;
#pragma unroll
  for (int k = 0; k < 4; ++k) {
    elw[base + k * kHD] = accl[k];
    erw[base + k * kHD] = accr[k];
  }
}

// ---------------- K2: attention (both heads per block) ----------------
// grid = B*8 (i-tiles of 8), block = 512.
__global__ __launch_bounds__(512) void gat_attn(
    const float* __restrict__ elw, const float* __restrict__ erw,
    const float* __restrict__ attn_a, const float* __restrict__ bias,
    float* __restrict__ out) {
  __shared__ float el[kH][kF][kD + 4];     // 67.6 KB
  __shared__ float sAT[kH][kF][8];         // alphas [h][j][i], 4 KB
  __shared__ float pbuf[4][kH][8][kD + 4]; // j-quarter partials, 33 KB

  const int b = blockIdx.x >> 3;
  const int i0 = (blockIdx.x & 7) << 3;
  const int t = threadIdx.x;

  // ---- stage: el only (both heads, all 64 src rows) ----
  {
    const float* elb = elw + b * (kF * kHD);
#pragma unroll
    for (int k = 0; k < 8; ++k) {
      const int s = t + (k << 9);        // 0..4095 float4 slots
      const int h = s >> 11;
      const int n = (s >> 5) & 63;
      const int dv = (s & 31) << 2;
      *(float4*)&el[h][n][dv] = *(const float4*)&elb[n * kHD + h * kD + dv];
    }
  }
  __syncthreads();

  // ---- scores + in-wave softmax ----
  // thread = q(4b) | jh(1b) | i(3b) | h(1b): the 32 threads sharing (h,i)
  // are one aligned 32-lane group -> shfl softmax, no LDS round-trip.
  // er/av are read from GLOBAL: <=2 distinct addrs per wave -> L1 broadcast,
  // off the DS pipe (halves scores' LDS instruction count).
  {
    const int q = t & 15;
    const int jh = (t >> 4) & 1;
    const int i = (t >> 5) & 7;
    const int h = t >> 8;
    const int j0 = q + (jh << 5);   // {0..15} u {32..47}
    const int j1 = j0 + 16;         // {16..31} u {48..63}
    const float* erp = erw + (b * kF + i0 + i) * kHD + h * kD;
    const float* avp = attn_a + h * kD;
    float e0 = 0.f, e1 = 0.f;
#pragma unroll
    for (int dv = 0; dv < kD; dv += 4) {
      const float4 rv = *(const float4*)&erp[dv];
      const float4 a4 = *(const float4*)&avp[dv];
      const float4 p0 = *(const float4*)&el[h][j0][dv];
      const float4 p1 = *(const float4*)&el[h][j1][dv];
      e0 = fmaf(lrelu(p0.x + rv.x), a4.x, e0);
      e0 = fmaf(lrelu(p0.y + rv.y), a4.y, e0);
      e0 = fmaf(lrelu(p0.z + rv.z), a4.z, e0);
      e0 = fmaf(lrelu(p0.w + rv.w), a4.w, e0);
      e1 = fmaf(lrelu(p1.x + rv.x), a4.x, e1);
      e1 = fmaf(lrelu(p1.y + rv.y), a4.y, e1);
      e1 = fmaf(lrelu(p1.z + rv.z), a4.z, e1);
      e1 = fmaf(lrelu(p1.w + rv.w), a4.w, e1);
    }
    // softmax over the 32-lane (h,i) group; each lane holds 2 of 64 j's
    float m = fmaxf(e0, e1);
#pragma unroll
    for (int off = 1; off < 32; off <<= 1) m = fmaxf(m, __shfl_xor(m, off));
    const float x0 = __expf(e0 - m);
    const float x1 = __expf(e1 - m);
    float s = x0 + x1;
#pragma unroll
    for (int off = 1; off < 32; off <<= 1) s += __shfl_xor(s, off);
    const float inv = 1.f / s;
    sAT[h][j0][i] = x0 * inv;
    sAT[h][j1][i] = x1 * inv;
  }
  __syncthreads();

  // ---- aggregate: thread = dq(5b) | ip(1b) | jq(2b) | h(1b) ----
  // 4i x 4d register tile; per j: 1 b128 alpha (broadcast) + 1 b128 el.
  {
    const int dq = t & 31;          // d = dq*4 .. +3
    const int ip = (t >> 5) & 1;    // i = ip*4 .. +3
    const int jq = (t >> 6) & 3;    // 16 j's
    const int h = t >> 8;
    float acc[4][4] = {};
    const int jbase = jq << 4;
#pragma unroll
    for (int jj = 0; jj < 16; ++jj) {
      const int j = jbase + jj;
      const float4 al = *(const float4*)&sAT[h][j][ip << 2];
      const float4 ev = *(const float4*)&el[h][j][dq << 2];
      acc[0][0] = fmaf(al.x, ev.x, acc[0][0]);
      acc[0][1] = fmaf(al.x, ev.y, acc[0][1]);
      acc[0][2] = fmaf(al.x, ev.z, acc[0][2]);
      acc[0][3] = fmaf(al.x, ev.w, acc[0][3]);
      acc[1][0] = fmaf(al.y, ev.x, acc[1][0]);
      acc[1][1] = fmaf(al.y, ev.y, acc[1][1]);
      acc[1][2] = fmaf(al.y, ev.z, acc[1][2]);
      acc[1][3] = fmaf(al.y, ev.w, acc[1][3]);
      acc[2][0] = fmaf(al.z, ev.x, acc[2][0]);
      acc[2][1] = fmaf(al.z, ev.y, acc[2][1]);
      acc[2][2] = fmaf(al.z, ev.z, acc[2][2]);
      acc[2][3] = fmaf(al.z, ev.w, acc[2][3]);
      acc[3][0] = fmaf(al.w, ev.x, acc[3][0]);
      acc[3][1] = fmaf(al.w, ev.y, acc[3][1]);
      acc[3][2] = fmaf(al.w, ev.z, acc[3][2]);
      acc[3][3] = fmaf(al.w, ev.w, acc[3][3]);
    }
#pragma unroll
    for (int ii = 0; ii < 4; ++ii) {
      float4 v;
      v.x = acc[ii][0]; v.y = acc[ii][1]; v.z = acc[ii][2]; v.w = acc[ii][3];
      *(float4*)&pbuf[jq][h][(ip << 2) + ii][dq << 2] = v;
    }
  }
  __syncthreads();

  // ---- final: sum jq partials + heads, bias, mean, store ----
  {
    const int i = t & 7;
    const int d = (t >> 3) << 1;    // d-pair
    float o0 = 0.f, o1 = 0.f;
#pragma unroll
    for (int jq = 0; jq < 4; ++jq) {
#pragma unroll
      for (int h = 0; h < 2; ++h) {
        const float2 v = *(const float2*)&pbuf[jq][h][i][d];
        o0 += v.x;
        o1 += v.y;
      }
    }
    const float b0 = bias[d] + bias[kD + d];
    const float b1 = bias[d + 1] + bias[kD + d + 1];
    float* ob = out + b * (kD * kF) + i0 + i;
    ob[d * kF] = 0.5f * (o0 + b0);
    ob[(d + 1) * kF] = 0.5f * (o1 + b1);
  }
}

extern "C" void kernel_launch(void* const* d_in, const int* in_sizes, int n_in,
                              void* d_out, int out_size, void* d_ws,
                              size_t ws_size, hipStream_t stream) {
  (void)in_sizes; (void)n_in; (void)ws_size; (void)out_size;
  const float* x = (const float*)d_in[0];
  const float* Wl = (const float*)d_in[1];
  const float* Wr = (const float*)d_in[2];
  const float* attn_a = (const float*)d_in[3];
  const float* bias = (const float*)d_in[4];
  float* out = (float*)d_out;

  float* elw = (float*)d_ws;                  // [B][64][256]
  float* erw = elw + (size_t)kB * kF * kHD;   // [B][64][256]

  gat_proj<<<dim3(kB * 8), dim3(512), 0, stream>>>(x, Wl, Wr, elw, erw);
  gat_attn<<<dim3(kB * 8), dim3(512), 0, stream>>>(elw, erw, attn_a, bias, out);
}